// Round 3
// baseline (917.428 us; speedup 1.0000x reference)
//
#include <hip/hip_runtime.h>
#include <hip/hip_bf16.h>

#define T_TOK 4096
#define DM 1024
#define DF 2048
#define NE 8

typedef __attribute__((ext_vector_type(8))) short bf16x8;
typedef __attribute__((ext_vector_type(4))) float f32x4;

__device__ __forceinline__ unsigned short f2bf(float f) {
  union { float f; unsigned int i; } v; v.f = f;
  unsigned int r = v.i + 0x7fffu + ((v.i >> 16) & 1u);
  return (unsigned short)(r >> 16);
}

__device__ __forceinline__ float bf2f(unsigned short u) {
  union { unsigned int i; float f; } v; v.i = ((unsigned int)u) << 16;
  return v.f;
}

__device__ __forceinline__ uint4 pack8(float4 a, float4 b) {
  uint4 r;
  r.x = (unsigned int)f2bf(a.x) | ((unsigned int)f2bf(a.y) << 16);
  r.y = (unsigned int)f2bf(a.z) | ((unsigned int)f2bf(a.w) << 16);
  r.z = (unsigned int)f2bf(b.x) | ((unsigned int)f2bf(b.y) << 16);
  r.w = (unsigned int)f2bf(b.z) | ((unsigned int)f2bf(b.w) << 16);
  return r;
}

// async global->LDS, 16B per lane; LDS dest = wave-uniform base + lane*16
__device__ __forceinline__ void gl2lds(const unsigned short* g, unsigned short* l) {
  __builtin_amdgcn_global_load_lds(
      (const __attribute__((address_space(1))) unsigned int*)g,
      (__attribute__((address_space(3))) unsigned int*)l, 16, 0, 0);
}

// ---------------- fused fp32 -> bf16 conversion for X + all 6 weight tensors ----------------
__global__ void cvt_all_kernel(const float* __restrict__ X,
                               const float* __restrict__ swg, const float* __restrict__ swu,
                               const float* __restrict__ swd,
                               const float* __restrict__ ewg, const float* __restrict__ ewu,
                               const float* __restrict__ ewd,
                               unsigned short* __restrict__ Xbf,
                               unsigned short* __restrict__ Wg_sh, unsigned short* __restrict__ Wu_sh,
                               unsigned short* __restrict__ Wd_sh,
                               unsigned short* __restrict__ Wg_ex, unsigned short* __restrict__ Wu_ex,
                               unsigned short* __restrict__ Wd_ex) {
  int b = blockIdx.x;
  const float* src; unsigned short* dst; int base;
  if (b < 2048)        { src = X;   dst = Xbf;   base = 0; }
  else if (b < 3072)   { src = swg; dst = Wg_sh; base = 2048; }
  else if (b < 4096)   { src = swu; dst = Wu_sh; base = 3072; }
  else if (b < 5120)   { src = swd; dst = Wd_sh; base = 4096; }
  else if (b < 13312)  { src = ewg; dst = Wg_ex; base = 5120; }
  else if (b < 21504)  { src = ewu; dst = Wu_ex; base = 13312; }
  else                 { src = ewd; dst = Wd_ex; base = 21504; }
  size_t idx = (size_t)(b - base) * 256 + threadIdx.x;
  float4 a = ((const float4*)src)[2 * idx];
  float4 c = ((const float4*)src)[2 * idx + 1];
  ((uint4*)dst)[idx] = pack8(a, c);
}

// ---------------- router ----------------
__global__ void router_kernel(const float* __restrict__ X, const float* __restrict__ RW,
                              const float* __restrict__ bias, int* __restrict__ cnt,
                              int* __restrict__ lists, float* __restrict__ wpair) {
  int t = blockIdx.x * 4 + (threadIdx.x >> 6);
  int lane = threadIdx.x & 63;
  float xv[16];
#pragma unroll
  for (int j = 0; j < 16; j++) xv[j] = X[(size_t)t * DM + lane + 64 * j];
  float logit[NE];
#pragma unroll
  for (int e = 0; e < NE; e++) {
    float s = 0.f;
#pragma unroll
    for (int j = 0; j < 16; j++) s += xv[j] * RW[e * DM + lane + 64 * j];
#pragma unroll
    for (int off = 32; off > 0; off >>= 1) s += __shfl_xor(s, off);
    logit[e] = s + bias[e];
  }
  if (lane == 0) {
    float mx = logit[0];
#pragma unroll
    for (int e = 1; e < NE; e++) mx = fmaxf(mx, logit[e]);
    float p[NE]; float sum = 0.f;
#pragma unroll
    for (int e = 0; e < NE; e++) { p[e] = expf(logit[e] - mx); sum += p[e]; }
    float inv = 1.f / sum;
    int e0 = 0, e1 = -1; float p0 = -1.f, p1 = -1.f;
#pragma unroll
    for (int e = 0; e < NE; e++) {
      float pe = p[e] * inv;
      if (pe > p0) { p1 = p0; e1 = e0; p0 = pe; e0 = e; }
      else if (pe > p1) { p1 = pe; e1 = e; }
    }
    float q0 = expf(p0), q1 = expf(p1);
    float qs = q0 + q1;
    wpair[t * 2] = q0 / qs; wpair[t * 2 + 1] = q1 / qs;
    int pos0 = atomicAdd(&cnt[e0], 1);
    lists[e0 * T_TOK + pos0] = t * 2;
    int pos1 = atomicAdd(&cnt[e1], 1);
    lists[e1 * T_TOK + pos1] = t * 2 + 1;
  }
}

// ---------------- merged gate+up GEMM: z=0 shared (dense), z=1..8 experts (gathered) ------
// double-buffered LDS, single barrier per K-step, DMA issued before compute
__global__ __launch_bounds__(256, 2) void gateup_kernel(
    const unsigned short* __restrict__ Xbf,
    const unsigned short* __restrict__ Wg_sh, const unsigned short* __restrict__ Wu_sh,
    const unsigned short* __restrict__ Wg_ex, const unsigned short* __restrict__ Wu_ex,
    unsigned short* __restrict__ Hsh, unsigned short* __restrict__ Hpair,
    const int* __restrict__ lists, const int* __restrict__ cnt) {
  int z = blockIdx.z;
  bool gather = (z > 0);
  int e = z - 1;
  int M = gather ? cnt[e] : T_TOK;
  int m0 = blockIdx.x * 128;
  if (m0 >= M) return;
  int n0 = blockIdx.y * 128;
  const unsigned short* Wg = gather ? Wg_ex + (size_t)e * DF * DM : Wg_sh;
  const unsigned short* Wu = gather ? Wu_ex + (size_t)e * DF * DM : Wu_sh;
  unsigned short* H = gather ? Hpair : Hsh;

  __shared__ alignas(16) unsigned short As[2][128 * 32];
  __shared__ alignas(16) unsigned short Bg[2][128 * 32];
  __shared__ alignas(16) unsigned short Bu[2][128 * 32];
  __shared__ int sp[128];

  int tid = threadIdx.x;
  if (tid < 128) {
    int i = m0 + tid;
    sp[tid] = gather ? lists[e * T_TOK + min(i, M - 1)] : i;
  }
  __syncthreads();

  int lane = tid & 63, wv = tid >> 6;
  // staging: wave wv owns regions 2wv,2wv+1; region r = rows [16r,16r+16) = 1024 B
  int r0 = 2 * wv, r1 = r0 + 1;
  int rowS0 = r0 * 16 + (lane >> 2), rowS1 = r1 * 16 + (lane >> 2);
  int kk = (lane & 3) * 8;
  int xr0 = gather ? (sp[rowS0] >> 1) : sp[rowS0];
  int xr1 = gather ? (sp[rowS1] >> 1) : sp[rowS1];
  const unsigned short* gA0 = Xbf + (size_t)xr0 * DM + kk;
  const unsigned short* gA1 = Xbf + (size_t)xr1 * DM + kk;
  const unsigned short* gG0 = Wg + (size_t)(n0 + rowS0) * DM + kk;
  const unsigned short* gG1 = Wg + (size_t)(n0 + rowS1) * DM + kk;
  const unsigned short* gU0 = Wu + (size_t)(n0 + rowS0) * DM + kk;
  const unsigned short* gU1 = Wu + (size_t)(n0 + rowS1) * DM + kk;
  int lo0 = r0 * 512, lo1 = r1 * 512;

  int wm = (wv >> 1) * 64, wn = (wv & 1) * 64;
  int quad = lane >> 4, l16 = lane & 15;

  f32x4 accg[4][4], accu[4][4];
  f32x4 zero = {0.f, 0.f, 0.f, 0.f};
#pragma unroll
  for (int i = 0; i < 4; i++)
#pragma unroll
    for (int j = 0; j < 4; j++) { accg[i][j] = zero; accu[i][j] = zero; }

#define STAGE_GU(buf, k0)                        \
  do {                                           \
    gl2lds(gA0 + (k0), &As[buf][lo0]);           \
    gl2lds(gA1 + (k0), &As[buf][lo1]);           \
    gl2lds(gG0 + (k0), &Bg[buf][lo0]);           \
    gl2lds(gG1 + (k0), &Bg[buf][lo1]);           \
    gl2lds(gU0 + (k0), &Bu[buf][lo0]);           \
    gl2lds(gU1 + (k0), &Bu[buf][lo1]);           \
  } while (0)

#define COMPUTE_GU(buf)                                                              \
  do {                                                                               \
    bf16x8 af[4], bgf[4], buf_[4];                                                   \
    _Pragma("unroll")                                                                \
    for (int mi = 0; mi < 4; mi++)                                                   \
      af[mi] = *(const bf16x8*)&As[buf][(wm + mi * 16 + l16) * 32 + quad * 8];       \
    _Pragma("unroll")                                                                \
    for (int ni = 0; ni < 4; ni++) {                                                 \
      bgf[ni] = *(const bf16x8*)&Bg[buf][(wn + ni * 16 + l16) * 32 + quad * 8];      \
      buf_[ni] = *(const bf16x8*)&Bu[buf][(wn + ni * 16 + l16) * 32 + quad * 8];     \
    }                                                                                \
    _Pragma("unroll")                                                                \
    for (int mi = 0; mi < 4; mi++)                                                   \
      _Pragma("unroll")                                                              \
      for (int ni = 0; ni < 4; ni++) {                                               \
        accg[mi][ni] = __builtin_amdgcn_mfma_f32_16x16x32_bf16(af[mi], bgf[ni],      \
                                                               accg[mi][ni], 0, 0, 0);\
        accu[mi][ni] = __builtin_amdgcn_mfma_f32_16x16x32_bf16(af[mi], buf_[ni],     \
                                                               accu[mi][ni], 0, 0, 0);\
      }                                                                              \
  } while (0)

  STAGE_GU(0, 0);
  for (int it = 0; it < DM / 32; it += 2) {
    __syncthreads();  // drains DMA for buf0; protects buf1 vs prior reads
    if (it + 1 < DM / 32) STAGE_GU(1, (it + 1) * 32);
    COMPUTE_GU(0);
    __syncthreads();  // drains DMA for buf1; protects buf0 vs prior reads
    if (it + 2 < DM / 32) STAGE_GU(0, (it + 2) * 32);
    COMPUTE_GU(1);
  }
#undef STAGE_GU
#undef COMPUTE_GU

  // epilogue: h = silu(g)*u -> bf16. D layout: row=quad*4+r, col=l16
#pragma unroll
  for (int mi = 0; mi < 4; mi++)
#pragma unroll
    for (int ni = 0; ni < 4; ni++)
#pragma unroll
      for (int r = 0; r < 4; r++) {
        int row = wm + mi * 16 + quad * 4 + r;
        if (m0 + row < M) {
          int hr = sp[row];
          int col = wn + ni * 16 + l16;
          float g = accg[mi][ni][r], u = accu[mi][ni][r];
          float h = (g / (1.f + __expf(-g))) * u;
          H[(size_t)hr * DF + n0 + col] = f2bf(h);
        }
      }
}

// ---------------- merged down GEMM: z=0 shared -> fp32 out; z=1..8 experts -> bf16 Opair --
__global__ __launch_bounds__(256, 2) void down_kernel(
    const unsigned short* __restrict__ Hsh, const unsigned short* __restrict__ Hpair,
    const unsigned short* __restrict__ Wd_sh, const unsigned short* __restrict__ Wd_ex,
    float* __restrict__ out, unsigned short* __restrict__ Opair,
    const int* __restrict__ lists, const int* __restrict__ cnt) {
  int z = blockIdx.z;
  bool gather = (z > 0);
  int e = z - 1;
  int M = gather ? cnt[e] : T_TOK;
  int m0 = blockIdx.x * 128;
  if (m0 >= M) return;
  int n0 = blockIdx.y * 128;
  const unsigned short* Wd = gather ? Wd_ex + (size_t)e * DM * DF : Wd_sh;
  const unsigned short* Hbase = gather ? Hpair : Hsh;

  __shared__ alignas(16) unsigned short As[2][128 * 32];
  __shared__ alignas(16) unsigned short Bs[2][128 * 32];
  __shared__ int sp[128];

  int tid = threadIdx.x;
  if (tid < 128) {
    int i = m0 + tid;
    sp[tid] = gather ? lists[e * T_TOK + min(i, M - 1)] : i;
  }
  __syncthreads();

  int lane = tid & 63, wv = tid >> 6;
  int r0 = 2 * wv, r1 = r0 + 1;
  int rowS0 = r0 * 16 + (lane >> 2), rowS1 = r1 * 16 + (lane >> 2);
  int kk = (lane & 3) * 8;
  const unsigned short* gA0 = Hbase + (size_t)sp[rowS0] * DF + kk;
  const unsigned short* gA1 = Hbase + (size_t)sp[rowS1] * DF + kk;
  const unsigned short* gB0 = Wd + (size_t)(n0 + rowS0) * DF + kk;
  const unsigned short* gB1 = Wd + (size_t)(n0 + rowS1) * DF + kk;
  int lo0 = r0 * 512, lo1 = r1 * 512;

  int wm = (wv >> 1) * 64, wn = (wv & 1) * 64;
  int quad = lane >> 4, l16 = lane & 15;

  f32x4 acc[4][4];
  f32x4 zero = {0.f, 0.f, 0.f, 0.f};
#pragma unroll
  for (int i = 0; i < 4; i++)
#pragma unroll
    for (int j = 0; j < 4; j++) acc[i][j] = zero;

#define STAGE_D(buf, k0)                         \
  do {                                           \
    gl2lds(gA0 + (k0), &As[buf][lo0]);           \
    gl2lds(gA1 + (k0), &As[buf][lo1]);           \
    gl2lds(gB0 + (k0), &Bs[buf][lo0]);           \
    gl2lds(gB1 + (k0), &Bs[buf][lo1]);           \
  } while (0)

#define COMPUTE_D(buf)                                                               \
  do {                                                                               \
    bf16x8 af[4], bf_[4];                                                            \
    _Pragma("unroll")                                                                \
    for (int mi = 0; mi < 4; mi++)                                                   \
      af[mi] = *(const bf16x8*)&As[buf][(wm + mi * 16 + l16) * 32 + quad * 8];       \
    _Pragma("unroll")                                                                \
    for (int ni = 0; ni < 4; ni++)                                                   \
      bf_[ni] = *(const bf16x8*)&Bs[buf][(wn + ni * 16 + l16) * 32 + quad * 8];      \
    _Pragma("unroll")                                                                \
    for (int mi = 0; mi < 4; mi++)                                                   \
      _Pragma("unroll")                                                              \
      for (int ni = 0; ni < 4; ni++)                                                 \
        acc[mi][ni] = __builtin_amdgcn_mfma_f32_16x16x32_bf16(af[mi], bf_[ni],       \
                                                              acc[mi][ni], 0, 0, 0); \
  } while (0)

  STAGE_D(0, 0);
  for (int it = 0; it < DF / 32; it += 2) {
    __syncthreads();
    if (it + 1 < DF / 32) STAGE_D(1, (it + 1) * 32);
    COMPUTE_D(0);
    __syncthreads();
    if (it + 2 < DF / 32) STAGE_D(0, (it + 2) * 32);
    COMPUTE_D(1);
  }
#undef STAGE_D
#undef COMPUTE_D

#pragma unroll
  for (int mi = 0; mi < 4; mi++)
#pragma unroll
    for (int ni = 0; ni < 4; ni++)
#pragma unroll
      for (int r = 0; r < 4; r++) {
        int row = wm + mi * 16 + quad * 4 + r;
        if (m0 + row < M) {
          int col = n0 + wn + ni * 16 + l16;
          float v = acc[mi][ni][r];
          if (gather) {
            Opair[(size_t)sp[row] * DM + col] = f2bf(v);
          } else {
            out[(size_t)sp[row] * DM + col] = v;
          }
        }
      }
}

// ---------------- combine: out[t] += w0*Opair[2t] + w1*Opair[2t+1] ----------------
__global__ void combine_kernel(float* __restrict__ out, const unsigned short* __restrict__ Opair,
                               const float* __restrict__ wpair) {
  int idx = blockIdx.x * 256 + threadIdx.x;  // 8-element chunk
  int t = idx / (DM / 8);
  int c = (idx % (DM / 8)) * 8;
  float w0 = wpair[2 * t], w1 = wpair[2 * t + 1];
  const uint4* o0 = (const uint4*)(Opair + (size_t)(2 * t) * DM + c);
  const uint4* o1 = (const uint4*)(Opair + (size_t)(2 * t + 1) * DM + c);
  float4* op = (float4*)(out + (size_t)t * DM + c);
  uint4 a = o0[0], b = o1[0];
  float4 x0 = op[0], x1 = op[1];
  x0.x += w0 * bf2f(a.x & 0xffff)  + w1 * bf2f(b.x & 0xffff);
  x0.y += w0 * bf2f(a.x >> 16)     + w1 * bf2f(b.x >> 16);
  x0.z += w0 * bf2f(a.y & 0xffff)  + w1 * bf2f(b.y & 0xffff);
  x0.w += w0 * bf2f(a.y >> 16)     + w1 * bf2f(b.y >> 16);
  x1.x += w0 * bf2f(a.z & 0xffff)  + w1 * bf2f(b.z & 0xffff);
  x1.y += w0 * bf2f(a.z >> 16)     + w1 * bf2f(b.z >> 16);
  x1.z += w0 * bf2f(a.w & 0xffff)  + w1 * bf2f(b.w & 0xffff);
  x1.w += w0 * bf2f(a.w >> 16)     + w1 * bf2f(b.w >> 16);
  op[0] = x0; op[1] = x1;
}

extern "C" void kernel_launch(void* const* d_in, const int* in_sizes, int n_in,
                              void* d_out, int out_size, void* d_ws, size_t ws_size,
                              hipStream_t stream) {
  const float* X       = (const float*)d_in[0];
  const float* RW      = (const float*)d_in[1];
  const float* bias    = (const float*)d_in[2];
  const float* sw_gate = (const float*)d_in[3];
  const float* sw_up   = (const float*)d_in[4];
  const float* sw_down = (const float*)d_in[5];
  const float* ew_gate = (const float*)d_in[6];
  const float* ew_up   = (const float*)d_in[7];
  const float* ew_down = (const float*)d_in[8];
  float* out = (float*)d_out;

  char* ws = (char*)d_ws;
  const size_t MB = 1 << 20;
  unsigned short* Xbf   = (unsigned short*)(ws);              //   8 MB
  unsigned short* Hsh   = (unsigned short*)(ws + 8 * MB);     //  16 MB
  unsigned short* Hpair = (unsigned short*)(ws + 24 * MB);    //  32 MB
  unsigned short* Wg_sh = (unsigned short*)(ws + 56 * MB);    //   4 MB
  unsigned short* Wu_sh = (unsigned short*)(ws + 60 * MB);    //   4 MB
  unsigned short* Wd_sh = (unsigned short*)(ws + 64 * MB);    //   4 MB
  unsigned short* Wg_ex = (unsigned short*)(ws + 68 * MB);    //  32 MB
  unsigned short* Wu_ex = (unsigned short*)(ws + 100 * MB);   //  32 MB
  unsigned short* Wd_ex = (unsigned short*)(ws + 132 * MB);   //  32 MB
  unsigned short* Opair = (unsigned short*)(ws + 164 * MB);   //  16 MB
  int*   lists = (int*)(ws + 180 * MB);                       // 128 KB
  float* wpair = (float*)(ws + 180 * MB + (128 << 10));       //  32 KB
  int*   cnt   = (int*)(ws + 180 * MB + (160 << 10));         //  32 B

  hipMemsetAsync(cnt, 0, NE * sizeof(int), stream);
  cvt_all_kernel<<<29696, 256, 0, stream>>>(X, sw_gate, sw_up, sw_down, ew_gate, ew_up, ew_down,
                                            Xbf, Wg_sh, Wu_sh, Wd_sh, Wg_ex, Wu_ex, Wd_ex);
  router_kernel<<<T_TOK / 4, 256, 0, stream>>>(X, RW, bias, cnt, lists, wpair);
  gateup_kernel<<<dim3(T_TOK / 128, DF / 128, NE + 1), 256, 0, stream>>>(
      Xbf, Wg_sh, Wu_sh, Wg_ex, Wu_ex, Hsh, Hpair, lists, cnt);
  down_kernel<<<dim3(T_TOK / 128, DM / 128, NE + 1), 256, 0, stream>>>(
      Hsh, Hpair, Wd_sh, Wd_ex, out, Opair, lists, cnt);
  combine_kernel<<<T_TOK * DM / 8 / 256, 256, 0, stream>>>(out, Opair, wpair);
}

// Round 4
// 590.729 us; speedup vs baseline: 1.5530x; 1.5530x over previous
//
#include <hip/hip_runtime.h>
#include <hip/hip_bf16.h>

#define T_TOK 4096
#define DM 1024
#define DF 2048
#define NE 8

typedef __attribute__((ext_vector_type(8))) short bf16x8;
typedef __attribute__((ext_vector_type(4))) float f32x4;

__device__ __forceinline__ unsigned short f2bf(float f) {
  union { float f; unsigned int i; } v; v.f = f;
  unsigned int r = v.i + 0x7fffu + ((v.i >> 16) & 1u);
  return (unsigned short)(r >> 16);
}

__device__ __forceinline__ float bf2f(unsigned short u) {
  union { unsigned int i; float f; } v; v.i = ((unsigned int)u) << 16;
  return v.f;
}

__device__ __forceinline__ uint4 pack8(float4 a, float4 b) {
  uint4 r;
  r.x = (unsigned int)f2bf(a.x) | ((unsigned int)f2bf(a.y) << 16);
  r.y = (unsigned int)f2bf(a.z) | ((unsigned int)f2bf(a.w) << 16);
  r.z = (unsigned int)f2bf(b.x) | ((unsigned int)f2bf(b.y) << 16);
  r.w = (unsigned int)f2bf(b.z) | ((unsigned int)f2bf(b.w) << 16);
  return r;
}

// async global->LDS, 16B per lane; LDS dest = wave-uniform base + lane*16
__device__ __forceinline__ void gl2lds(const unsigned short* g, unsigned short* l) {
  __builtin_amdgcn_global_load_lds(
      (const __attribute__((address_space(1))) unsigned int*)g,
      (__attribute__((address_space(3))) unsigned int*)l, 16, 0, 0);
}

// ---------------- fused fp32 -> bf16 conversion for X + all 6 weight tensors ----------------
__global__ void cvt_all_kernel(const float* __restrict__ X,
                               const float* __restrict__ swg, const float* __restrict__ swu,
                               const float* __restrict__ swd,
                               const float* __restrict__ ewg, const float* __restrict__ ewu,
                               const float* __restrict__ ewd,
                               unsigned short* __restrict__ Xbf,
                               unsigned short* __restrict__ Wg_sh, unsigned short* __restrict__ Wu_sh,
                               unsigned short* __restrict__ Wd_sh,
                               unsigned short* __restrict__ Wg_ex, unsigned short* __restrict__ Wu_ex,
                               unsigned short* __restrict__ Wd_ex) {
  int b = blockIdx.x;
  const float* src; unsigned short* dst; int base;
  if (b < 2048)        { src = X;   dst = Xbf;   base = 0; }
  else if (b < 3072)   { src = swg; dst = Wg_sh; base = 2048; }
  else if (b < 4096)   { src = swu; dst = Wu_sh; base = 3072; }
  else if (b < 5120)   { src = swd; dst = Wd_sh; base = 4096; }
  else if (b < 13312)  { src = ewg; dst = Wg_ex; base = 5120; }
  else if (b < 21504)  { src = ewu; dst = Wu_ex; base = 13312; }
  else                 { src = ewd; dst = Wd_ex; base = 21504; }
  size_t idx = (size_t)(b - base) * 256 + threadIdx.x;
  float4 a = ((const float4*)src)[2 * idx];
  float4 c = ((const float4*)src)[2 * idx + 1];
  ((uint4*)dst)[idx] = pack8(a, c);
}

// ---------------- router ----------------
__global__ void router_kernel(const float* __restrict__ X, const float* __restrict__ RW,
                              const float* __restrict__ bias, int* __restrict__ cnt,
                              int* __restrict__ lists, float* __restrict__ wpair) {
  int t = blockIdx.x * 4 + (threadIdx.x >> 6);
  int lane = threadIdx.x & 63;
  float xv[16];
#pragma unroll
  for (int j = 0; j < 16; j++) xv[j] = X[(size_t)t * DM + lane + 64 * j];
  float logit[NE];
#pragma unroll
  for (int e = 0; e < NE; e++) {
    float s = 0.f;
#pragma unroll
    for (int j = 0; j < 16; j++) s += xv[j] * RW[e * DM + lane + 64 * j];
#pragma unroll
    for (int off = 32; off > 0; off >>= 1) s += __shfl_xor(s, off);
    logit[e] = s + bias[e];
  }
  if (lane == 0) {
    float mx = logit[0];
#pragma unroll
    for (int e = 1; e < NE; e++) mx = fmaxf(mx, logit[e]);
    float p[NE]; float sum = 0.f;
#pragma unroll
    for (int e = 0; e < NE; e++) { p[e] = expf(logit[e] - mx); sum += p[e]; }
    float inv = 1.f / sum;
    int e0 = 0, e1 = -1; float p0 = -1.f, p1 = -1.f;
#pragma unroll
    for (int e = 0; e < NE; e++) {
      float pe = p[e] * inv;
      if (pe > p0) { p1 = p0; e1 = e0; p0 = pe; e0 = e; }
      else if (pe > p1) { p1 = pe; e1 = e; }
    }
    float q0 = expf(p0), q1 = expf(p1);
    float qs = q0 + q1;
    wpair[t * 2] = q0 / qs; wpair[t * 2 + 1] = q1 / qs;
    int pos0 = atomicAdd(&cnt[e0], 1);
    lists[e0 * T_TOK + pos0] = t * 2;
    int pos1 = atomicAdd(&cnt[e1], 1);
    lists[e1 * T_TOK + pos1] = t * 2 + 1;
  }
}

// ---------------- gate+up GEMM, 128 rows x 64 cols of BOTH g and u per block -------------
// waves 0,1 = gate (row halves), waves 2,3 = up; u crosses via LDS in epilogue.
// 64 AGPR acc/wave -> 3 waves/SIMD target. BK=64, single-buffer, XOR-swizzled LDS.
__global__ __launch_bounds__(256, 3) void gateup_kernel(
    const unsigned short* __restrict__ Xbf,
    const unsigned short* __restrict__ Wg_sh, const unsigned short* __restrict__ Wu_sh,
    const unsigned short* __restrict__ Wg_ex, const unsigned short* __restrict__ Wu_ex,
    unsigned short* __restrict__ Hsh, unsigned short* __restrict__ Hpair,
    const int* __restrict__ lists, const int* __restrict__ cnt) {
  int z = blockIdx.z;
  bool gather = (z > 0);
  int e = z - 1;
  int M = gather ? cnt[e] : T_TOK;
  // XCD swizzle: XCD i (= lin%8) owns n-tiles {4i..4i+3} -> weight tiles stay in its L2
  int lin = blockIdx.x + 32 * blockIdx.y;                 // 0..1023
  int m0 = (lin >> 5) * 128;
  int n0 = (4 * (lin & 7) + ((lin >> 3) & 3)) * 64;
  if (m0 >= M) return;
  const unsigned short* Wg = gather ? Wg_ex + (size_t)e * DF * DM : Wg_sh;
  const unsigned short* Wu = gather ? Wu_ex + (size_t)e * DF * DM : Wu_sh;
  unsigned short* H = gather ? Hpair : Hsh;

  __shared__ union {
    struct {
      unsigned short A[128 * 64];    // 16 KB, [row][k] with XOR-swizzled 16B chunks
      unsigned short B[2][64 * 64];  // 8 KB each: [0]=gate, [1]=up
    } s;
    float U[128 * 66];               // epilogue u exchange (padded)
  } sm;
  __shared__ int sp[128];

  int tid = threadIdx.x;
  if (tid < 128) {
    int i = m0 + tid;
    sp[tid] = gather ? lists[e * T_TOK + min(i, M - 1)] : i;
  }
  __syncthreads();

  int lane = tid & 63, wv = tid >> 6;
  // staging: 8 DMAs/wave, each 8 rows x 128B. Global k-chunk XOR-swizzled by row so that
  // the fixed LDS lane*16 mapping lands a conflict-free layout.
  int rl = lane >> 3;                          // row within DMA (0..7)
  int swz = ((lane & 7) ^ rl) * 8;             // swizzled k offset (elems)
  const unsigned short* P[8];
  unsigned short* L[8];
#pragma unroll
  for (int d = 0; d < 8; d++) {
    if (wv < 2) {
      int row = wv * 64 + 8 * d + rl;
      int t = sp[row];
      int xr = gather ? (t >> 1) : t;
      P[d] = Xbf + (size_t)xr * DM + swz;
      L[d] = &sm.s.A[(wv * 64 + 8 * d) * 64];
    } else {
      int row = n0 + 8 * d + rl;
      P[d] = (wv == 2 ? Wg : Wu) + (size_t)row * DM + swz;
      L[d] = &sm.s.B[wv - 2][(8 * d) * 64];
    }
  }

  int wrow = (wv & 1) * 64;   // A-row half this wave computes
  int mat = wv >> 1;          // 0 = gate, 1 = up
  int quad = lane >> 4, l16 = lane & 15, r7 = l16 & 7;

  // frag base pointers; chunk index kc stored at slot kc ^ (row&7)
  const bf16x8* A0 = (const bf16x8*)&sm.s.A[(wrow + l16) * 64 + ((0 + quad) ^ r7) * 8];
  const bf16x8* A1 = (const bf16x8*)&sm.s.A[(wrow + l16) * 64 + ((4 + quad) ^ r7) * 8];
  const bf16x8* B0 = (const bf16x8*)&sm.s.B[mat][l16 * 64 + ((0 + quad) ^ r7) * 8];
  const bf16x8* B1 = (const bf16x8*)&sm.s.B[mat][l16 * 64 + ((4 + quad) ^ r7) * 8];

  f32x4 acc[4][4];
  f32x4 zero = {0.f, 0.f, 0.f, 0.f};
#pragma unroll
  for (int i = 0; i < 4; i++)
#pragma unroll
    for (int j = 0; j < 4; j++) acc[i][j] = zero;

  for (int k0 = 0; k0 < DM; k0 += 64) {
    __syncthreads();
#pragma unroll
    for (int d = 0; d < 8; d++) gl2lds(P[d] + k0, L[d]);
    __syncthreads();
    {
      bf16x8 af[4], bf[4];
#pragma unroll
      for (int mi = 0; mi < 4; mi++) af[mi] = A0[mi * 128];
#pragma unroll
      for (int ni = 0; ni < 4; ni++) bf[ni] = B0[ni * 128];
#pragma unroll
      for (int mi = 0; mi < 4; mi++)
#pragma unroll
        for (int ni = 0; ni < 4; ni++)
          acc[mi][ni] = __builtin_amdgcn_mfma_f32_16x16x32_bf16(af[mi], bf[ni], acc[mi][ni], 0, 0, 0);
#pragma unroll
      for (int mi = 0; mi < 4; mi++) af[mi] = A1[mi * 128];
#pragma unroll
      for (int ni = 0; ni < 4; ni++) bf[ni] = B1[ni * 128];
#pragma unroll
      for (int mi = 0; mi < 4; mi++)
#pragma unroll
        for (int ni = 0; ni < 4; ni++)
          acc[mi][ni] = __builtin_amdgcn_mfma_f32_16x16x32_bf16(af[mi], bf[ni], acc[mi][ni], 0, 0, 0);
    }
  }

  // epilogue: up waves publish u via LDS; gate waves compute h = silu(g)*u and store
  __syncthreads();
  if (mat == 1) {
#pragma unroll
    for (int mi = 0; mi < 4; mi++)
#pragma unroll
      for (int ni = 0; ni < 4; ni++)
#pragma unroll
        for (int r = 0; r < 4; r++) {
          int row = wrow + mi * 16 + quad * 4 + r;
          int col = ni * 16 + l16;
          sm.U[row * 66 + col] = acc[mi][ni][r];
        }
  }
  __syncthreads();
  if (mat == 0) {
#pragma unroll
    for (int mi = 0; mi < 4; mi++)
#pragma unroll
      for (int ni = 0; ni < 4; ni++)
#pragma unroll
        for (int r = 0; r < 4; r++) {
          int row = wrow + mi * 16 + quad * 4 + r;
          if (m0 + row < M) {
            int col = ni * 16 + l16;
            float g = acc[mi][ni][r];
            float u = sm.U[row * 66 + col];
            float h = (g / (1.f + __expf(-g))) * u;
            H[(size_t)sp[row] * DF + n0 + col] = f2bf(h);
          }
        }
  }
}

// ---------------- down GEMM: 128x128 m97 shape, 64 AGPR/wave, BK=64, swizzled LDS --------
__global__ __launch_bounds__(256, 3) void down_kernel(
    const unsigned short* __restrict__ Hsh, const unsigned short* __restrict__ Hpair,
    const unsigned short* __restrict__ Wd_sh, const unsigned short* __restrict__ Wd_ex,
    float* __restrict__ out, unsigned short* __restrict__ Opair,
    const int* __restrict__ lists, const int* __restrict__ cnt) {
  int z = blockIdx.z;
  bool gather = (z > 0);
  int e = z - 1;
  int M = gather ? cnt[e] : T_TOK;
  // XCD swizzle: XCD i owns n-tile i
  int lin = blockIdx.x + 32 * blockIdx.y;   // 0..255
  int m0 = (lin >> 3) * 128;
  int n0 = (lin & 7) * 128;
  if (m0 >= M) return;
  const unsigned short* Wd = gather ? Wd_ex + (size_t)e * DM * DF : Wd_sh;
  const unsigned short* Hbase = gather ? Hpair : Hsh;

  __shared__ struct {
    unsigned short A[128 * 64];   // 16 KB
    unsigned short B[128 * 64];   // 16 KB
  } sm;
  __shared__ int sp[128];

  int tid = threadIdx.x;
  if (tid < 128) {
    int i = m0 + tid;
    sp[tid] = gather ? lists[e * T_TOK + min(i, M - 1)] : i;
  }
  __syncthreads();

  int lane = tid & 63, wv = tid >> 6;
  int rl = lane >> 3;
  int swz = ((lane & 7) ^ rl) * 8;
  const unsigned short* P[8];
  unsigned short* L[8];
#pragma unroll
  for (int d = 0; d < 8; d++) {
    if (wv < 2) {
      int row = wv * 64 + 8 * d + rl;
      P[d] = Hbase + (size_t)sp[row] * DF + swz;
      L[d] = &sm.A[(wv * 64 + 8 * d) * 64];
    } else {
      int row = n0 + (wv - 2) * 64 + 8 * d + rl;
      P[d] = Wd + (size_t)row * DF + swz;
      L[d] = &sm.B[((wv - 2) * 64 + 8 * d) * 64];
    }
  }

  int wm = (wv >> 1) * 64, wn = (wv & 1) * 64;
  int quad = lane >> 4, l16 = lane & 15, r7 = l16 & 7;

  const bf16x8* A0 = (const bf16x8*)&sm.A[(wm + l16) * 64 + ((0 + quad) ^ r7) * 8];
  const bf16x8* A1 = (const bf16x8*)&sm.A[(wm + l16) * 64 + ((4 + quad) ^ r7) * 8];
  const bf16x8* B0 = (const bf16x8*)&sm.B[(wn + l16) * 64 + ((0 + quad) ^ r7) * 8];
  const bf16x8* B1 = (const bf16x8*)&sm.B[(wn + l16) * 64 + ((4 + quad) ^ r7) * 8];

  f32x4 acc[4][4];
  f32x4 zero = {0.f, 0.f, 0.f, 0.f};
#pragma unroll
  for (int i = 0; i < 4; i++)
#pragma unroll
    for (int j = 0; j < 4; j++) acc[i][j] = zero;

  for (int k0 = 0; k0 < DF; k0 += 64) {
    __syncthreads();
#pragma unroll
    for (int d = 0; d < 8; d++) gl2lds(P[d] + k0, L[d]);
    __syncthreads();
    {
      bf16x8 af[4], bf[4];
#pragma unroll
      for (int mi = 0; mi < 4; mi++) af[mi] = A0[mi * 128];
#pragma unroll
      for (int ni = 0; ni < 4; ni++) bf[ni] = B0[ni * 128];
#pragma unroll
      for (int mi = 0; mi < 4; mi++)
#pragma unroll
        for (int ni = 0; ni < 4; ni++)
          acc[mi][ni] = __builtin_amdgcn_mfma_f32_16x16x32_bf16(af[mi], bf[ni], acc[mi][ni], 0, 0, 0);
#pragma unroll
      for (int mi = 0; mi < 4; mi++) af[mi] = A1[mi * 128];
#pragma unroll
      for (int ni = 0; ni < 4; ni++) bf[ni] = B1[ni * 128];
#pragma unroll
      for (int mi = 0; mi < 4; mi++)
#pragma unroll
        for (int ni = 0; ni < 4; ni++)
          acc[mi][ni] = __builtin_amdgcn_mfma_f32_16x16x32_bf16(af[mi], bf[ni], acc[mi][ni], 0, 0, 0);
    }
  }

#pragma unroll
  for (int mi = 0; mi < 4; mi++)
#pragma unroll
    for (int ni = 0; ni < 4; ni++)
#pragma unroll
      for (int r = 0; r < 4; r++) {
        int row = wm + mi * 16 + quad * 4 + r;
        if (m0 + row < M) {
          int col = n0 + wn + ni * 16 + l16;
          float v = acc[mi][ni][r];
          if (gather) {
            Opair[(size_t)sp[row] * DM + col] = f2bf(v);
          } else {
            out[(size_t)sp[row] * DM + col] = v;
          }
        }
      }
}

// ---------------- combine: out[t] += w0*Opair[2t] + w1*Opair[2t+1] ----------------
__global__ void combine_kernel(float* __restrict__ out, const unsigned short* __restrict__ Opair,
                               const float* __restrict__ wpair) {
  int idx = blockIdx.x * 256 + threadIdx.x;  // 8-element chunk
  int t = idx / (DM / 8);
  int c = (idx % (DM / 8)) * 8;
  float w0 = wpair[2 * t], w1 = wpair[2 * t + 1];
  const uint4* o0 = (const uint4*)(Opair + (size_t)(2 * t) * DM + c);
  const uint4* o1 = (const uint4*)(Opair + (size_t)(2 * t + 1) * DM + c);
  float4* op = (float4*)(out + (size_t)t * DM + c);
  uint4 a = o0[0], b = o1[0];
  float4 x0 = op[0], x1 = op[1];
  x0.x += w0 * bf2f(a.x & 0xffff)  + w1 * bf2f(b.x & 0xffff);
  x0.y += w0 * bf2f(a.x >> 16)     + w1 * bf2f(b.x >> 16);
  x0.z += w0 * bf2f(a.y & 0xffff)  + w1 * bf2f(b.y & 0xffff);
  x0.w += w0 * bf2f(a.y >> 16)     + w1 * bf2f(b.y >> 16);
  x1.x += w0 * bf2f(a.z & 0xffff)  + w1 * bf2f(b.z & 0xffff);
  x1.y += w0 * bf2f(a.z >> 16)     + w1 * bf2f(b.z >> 16);
  x1.z += w0 * bf2f(a.w & 0xffff)  + w1 * bf2f(b.w & 0xffff);
  x1.w += w0 * bf2f(a.w >> 16)     + w1 * bf2f(b.w >> 16);
  op[0] = x0; op[1] = x1;
}

extern "C" void kernel_launch(void* const* d_in, const int* in_sizes, int n_in,
                              void* d_out, int out_size, void* d_ws, size_t ws_size,
                              hipStream_t stream) {
  const float* X       = (const float*)d_in[0];
  const float* RW      = (const float*)d_in[1];
  const float* bias    = (const float*)d_in[2];
  const float* sw_gate = (const float*)d_in[3];
  const float* sw_up   = (const float*)d_in[4];
  const float* sw_down = (const float*)d_in[5];
  const float* ew_gate = (const float*)d_in[6];
  const float* ew_up   = (const float*)d_in[7];
  const float* ew_down = (const float*)d_in[8];
  float* out = (float*)d_out;

  char* ws = (char*)d_ws;
  const size_t MB = 1 << 20;
  unsigned short* Xbf   = (unsigned short*)(ws);              //   8 MB
  unsigned short* Hsh   = (unsigned short*)(ws + 8 * MB);     //  16 MB
  unsigned short* Hpair = (unsigned short*)(ws + 24 * MB);    //  32 MB
  unsigned short* Wg_sh = (unsigned short*)(ws + 56 * MB);    //   4 MB
  unsigned short* Wu_sh = (unsigned short*)(ws + 60 * MB);    //   4 MB
  unsigned short* Wd_sh = (unsigned short*)(ws + 64 * MB);    //   4 MB
  unsigned short* Wg_ex = (unsigned short*)(ws + 68 * MB);    //  32 MB
  unsigned short* Wu_ex = (unsigned short*)(ws + 100 * MB);   //  32 MB
  unsigned short* Wd_ex = (unsigned short*)(ws + 132 * MB);   //  32 MB
  unsigned short* Opair = (unsigned short*)(ws + 164 * MB);   //  16 MB
  int*   lists = (int*)(ws + 180 * MB);                       // 128 KB
  float* wpair = (float*)(ws + 180 * MB + (128 << 10));       //  32 KB
  int*   cnt   = (int*)(ws + 180 * MB + (160 << 10));         //  32 B

  hipMemsetAsync(cnt, 0, NE * sizeof(int), stream);
  cvt_all_kernel<<<29696, 256, 0, stream>>>(X, sw_gate, sw_up, sw_down, ew_gate, ew_up, ew_down,
                                            Xbf, Wg_sh, Wu_sh, Wd_sh, Wg_ex, Wu_ex, Wd_ex);
  router_kernel<<<T_TOK / 4, 256, 0, stream>>>(X, RW, bias, cnt, lists, wpair);
  gateup_kernel<<<dim3(32, 32, NE + 1), 256, 0, stream>>>(
      Xbf, Wg_sh, Wu_sh, Wg_ex, Wu_ex, Hsh, Hpair, lists, cnt);
  down_kernel<<<dim3(32, 8, NE + 1), 256, 0, stream>>>(
      Hsh, Hpair, Wd_sh, Wd_ex, out, Opair, lists, cnt);
  combine_kernel<<<T_TOK * DM / 8 / 256, 256, 0, stream>>>(out, Opair, wpair);
}